// Round 2
// baseline (121.767 us; speedup 1.0000x reference)
//
#include <hip/hip_runtime.h>

// out[c, y, w] = x[p, c, oy, ox]
//   iy = y / 126, jx = w / 126  (clamp to 8 never triggers for y,w < 1024)
//   oy = y - iy*126, ox = w - jx*126, p = iy*9 + jx
// x: (81, 64, 128, 128) f32; out: (64, 1024, 1024) f32. Pure gather, memory-bound.
//
// Structure fact: segment boundaries (w = 126k) are all EVEN, so every aligned
// pair (w, w+1) lies in ONE segment and its input address is 8B-aligned
// (ox = w - 126*jx is even). => 8 outputs/thread as 4x float2 loads +
// 2x float4 stores, no branches, no split groups.

__global__ __launch_bounds__(256) void patch_gather_kernel(
    const float* __restrict__ x, float* __restrict__ out, unsigned n_groups) {
    const unsigned stride = gridDim.x * blockDim.x;
    for (unsigned g = blockIdx.x * blockDim.x + threadIdx.x; g < n_groups; g += stride) {
        const unsigned idx = g << 3;               // first of 8 consecutive outputs
        const unsigned c  = idx >> 20;             // H*W = 2^20
        const unsigned y  = (idx >> 10) & 1023u;
        const unsigned w0 = idx & 1023u;           // multiple of 8, no row crossing

        const unsigned iy = y / 126u;              // magic-mul
        const unsigned oy = y - iy * 126u;

        // base address for (iy-row of patches, channel c, row oy):
        // addr = ((p*64 + c) << 14) + (oy << 7) + ox,  p = iy*9 + jx
        //      = A + (jx << 20) + ox
        const size_t A = ((size_t)(iy * 576u + c) << 14) + (oy << 7);

        float2 pr[4];
        #pragma unroll
        for (int k = 0; k < 4; ++k) {
            const unsigned w  = w0 + 2u * k;
            const unsigned jx = w / 126u;          // magic-mul
            const unsigned ox = w - jx * 126u;     // even
            pr[k] = *reinterpret_cast<const float2*>(&x[A + ((size_t)jx << 20) + ox]);
        }

        float4 r0, r1;
        r0.x = pr[0].x; r0.y = pr[0].y; r0.z = pr[1].x; r0.w = pr[1].y;
        r1.x = pr[2].x; r1.y = pr[2].y; r1.z = pr[3].x; r1.w = pr[3].y;
        *reinterpret_cast<float4*>(&out[idx])     = r0;
        *reinterpret_cast<float4*>(&out[idx + 4]) = r1;
    }
}

extern "C" void kernel_launch(void* const* d_in, const int* in_sizes, int n_in,
                              void* d_out, int out_size, void* d_ws, size_t ws_size,
                              hipStream_t stream) {
    const float* x = (const float*)d_in[0];
    float* out = (float*)d_out;

    const unsigned n_groups = (unsigned)(out_size / 8);   // 8,388,608
    const int block = 256;
    unsigned total_blocks = (n_groups + block - 1) / block;
    unsigned grid = total_blocks < 2048u ? total_blocks : 2048u;

    patch_gather_kernel<<<grid, block, 0, stream>>>(x, out, n_groups);
}

// Round 3
// 115.988 us; speedup vs baseline: 1.0498x; 1.0498x over previous
//
#include <hip/hip_runtime.h>

// out[c, y, w] = x[p, c, oy, ox]
//   iy = y / 126, jx = w / 126  (clamp to 8 never triggers for y,w < 1024)
//   oy = y - iy*126, ox = w - jx*126, p = iy*9 + jx
// x: (81, 64, 128, 128) f32; out: (64, 1024, 1024) f32. Pure gather, memory-bound.
//
// Round-3 structure: one thread = one output PAIR (2 floats).
//  - pairs never split a jx-segment (boundaries 126k are even)
//  - input pair addr is 8-B aligned (base is mult of 128 floats, ox even)
//  - lane i owns pair base+i  => every global_load_dwordx2 / store_dwordx2 is
//    512 B/wave fully-dense contiguous (100% per-instruction cache-line use).
//    Rounds 1-2 had lanes strided 4x wider than the data per instruction
//    (25% line utilization on loads) -> stuck at ~4.3 TB/s.
//  - unroll x4 at +blockDim stride for ILP.

__global__ __launch_bounds__(256) void patch_gather_kernel(
    const float* __restrict__ x, float* __restrict__ out, unsigned n_pairs) {
    const unsigned tid = threadIdx.x;
    const unsigned chunk = blockDim.x * 4u;                 // pairs per block-iter
    const unsigned stride = gridDim.x * chunk;
    for (unsigned base = blockIdx.x * chunk + tid; base < n_pairs; base += stride) {
        #pragma unroll
        for (int k = 0; k < 4; ++k) {
            const unsigned q = base + (unsigned)k * 256u;   // pair index, lanes contiguous
            if (q >= n_pairs) break;                        // (exact fit in practice)
            const unsigned idx = q << 1;                    // flat output index (even)
            const unsigned c  = idx >> 20;                  // H*W = 2^20
            const unsigned y  = (idx >> 10) & 1023u;
            const unsigned w0 = idx & 1023u;                // even

            const unsigned iy = y / 126u;                   // magic-mul
            const unsigned oy = y - iy * 126u;
            const unsigned jx = w0 / 126u;                  // magic-mul
            const unsigned ox = w0 - jx * 126u;             // even

            // addr = ((p*64 + c) << 14) + (oy << 7) + ox,  p = iy*9 + jx
            const size_t addr = ((size_t)(iy * 576u + c) << 14)
                              + ((size_t)jx << 20) + (oy << 7) + ox;
            const float2 v = *reinterpret_cast<const float2*>(&x[addr]);
            *reinterpret_cast<float2*>(&out[idx]) = v;
        }
    }
}

extern "C" void kernel_launch(void* const* d_in, const int* in_sizes, int n_in,
                              void* d_out, int out_size, void* d_ws, size_t ws_size,
                              hipStream_t stream) {
    const float* x = (const float*)d_in[0];
    float* out = (float*)d_out;

    const unsigned n_pairs = (unsigned)(out_size / 2);      // 33,554,432
    const int block = 256;
    const unsigned chunk = block * 4;
    unsigned total_blocks = (n_pairs + chunk - 1) / chunk;
    unsigned grid = total_blocks < 2048u ? total_blocks : 2048u;

    patch_gather_kernel<<<grid, block, 0, stream>>>(x, out, n_pairs);
}